// Round 3
// baseline (907.536 us; speedup 1.0000x reference)
//
#include <hip/hip_runtime.h>
#include <hip/hip_bf16.h>

typedef __hip_bfloat16 bf16;

#define NN   100000
#define EE   1600000
#define FH   32
#define FOUT 4

__device__ __forceinline__ float b2f(bf16 v) { return __bfloat162float(v); }

// Dtype-robust loads: flg[0]=1 -> float arrays are fp32 else bf16;
// flg[1]=1 -> edge_index is int64 else int32. Wave-uniform branches.
__device__ __forceinline__ float ldf(const void* p, int i, int f32) {
    return f32 ? ((const float*)p)[i] : b2f(((const bf16*)p)[i]);
}
__device__ __forceinline__ int ldi(const void* p, int i, int i64f) {
    return i64f ? (int)(((const long long*)p)[i]) : ((const int*)p)[i];
}
// Output follows the float input dtype (reference computes in input precision).
__device__ __forceinline__ void stf(void* p, int i, int f32, float v) {
    if (f32) ((float*)p)[i] = v;
    else     ((bf16*)p)[i] = __float2bfloat16(v);
}

// ---------------------------------------------------------------------------
// Kernel 0: dtype detection. 1 block, 256 threads.
// float test: reinterpret first 256 bf16 of x. True-bf16 normals are |v|<~6.
//   fp32-read-as-bf16: even slots (low mantissa halves) have random exponent
//   bits -> |v|>100 or NaN/Inf w/ prob ~0.5 each; 128 slots -> miss ~2^-128.
// int test: int64 ids < 2^31 => all odd 32-bit words are 0; int32 random ids
//   => odd words nonzero w/ prob ~1-1e-5 each.
// ---------------------------------------------------------------------------
__global__ __launch_bounds__(256) void k_detect(const void* __restrict__ x,
                                                const void* __restrict__ ei,
                                                int* __restrict__ flg) {
    __shared__ int s_f32[256], s_oddnz[256];
    int t = threadIdx.x;
    float v = b2f(((const bf16*)x)[t]);
    int bad = (!isfinite(v)) || (fabsf(v) > 100.f);
    s_f32[t] = bad;
    int w32 = ((const int*)ei)[t];
    s_oddnz[t] = ((t & 1) && (w32 != 0)) ? 1 : 0;
    __syncthreads();
    if (t == 0) {
        int f32 = 0, oddnz = 0;
        for (int i = 0; i < 256; i++) { f32 |= s_f32[i]; oddnz |= s_oddnz[i]; }
        flg[0] = f32;           // 1 => fp32 float arrays (and fp32 output)
        flg[1] = oddnz ? 0 : 1; // 1 => int64 edge_index
    }
}

// ---------------------------------------------------------------------------
// Kernel 1: degree = segment_sum(w, src), w = self-loop-zeroed edge_weight
// ---------------------------------------------------------------------------
__global__ __launch_bounds__(256) void k_deg(const void* __restrict__ ei,
                                             const void* __restrict__ ew,
                                             const int* __restrict__ flg,
                                             float* __restrict__ deg) {
    int e = blockIdx.x * 256 + threadIdx.x;
    if (e >= EE) return;
    int f32 = flg[0], i64 = flg[1];
    int s = ldi(ei, e, i64);
    int d = ldi(ei, EE + e, i64);
    float w = (s == d) ? 0.f : ldf(ew, e, f32);
    if (w != 0.f) atomicAdd(&deg[s], w);
}

// ---------------------------------------------------------------------------
// Kernel 2: deg -> dinv = deg>0 ? rsqrt(deg) : 0   (in place, fp32 ws)
// ---------------------------------------------------------------------------
__global__ __launch_bounds__(256) void k_dinv(float* __restrict__ deg) {
    int i = blockIdx.x * 256 + threadIdx.x;
    if (i >= NN) return;
    float dv = deg[i];
    deg[i] = (dv > 0.f) ? rsqrtf(dv) : 0.f;
}

// ---------------------------------------------------------------------------
// Kernel 3: per (edge,feature): nw = dinv[s]*w*dinv[d]; store nw;
//           AX[d] += -nw * x[s];  AH[d] += -nw * H[s].  32 lanes/edge.
// ---------------------------------------------------------------------------
__global__ __launch_bounds__(256) void k_edge_agg1(const void* __restrict__ ei,
                                                   const void* __restrict__ ew,
                                                   const int* __restrict__ flg,
                                                   const float* __restrict__ dinv,
                                                   const void* __restrict__ x,
                                                   const void* __restrict__ H,
                                                   float* __restrict__ nw,
                                                   float* __restrict__ AX,
                                                   float* __restrict__ AH) {
    unsigned t = blockIdx.x * 256u + threadIdx.x;
    if (t >= (unsigned)EE * FH) return;
    int e = (int)(t >> 5);
    int f = (int)(t & 31);
    int f32 = flg[0], i64 = flg[1];
    int s = ldi(ei, e, i64);
    int d = ldi(ei, EE + e, i64);
    float w = (s == d) ? 0.f : ldf(ew, e, f32);
    float nwv = dinv[s] * w * dinv[d];
    if (f == 0) nw[e] = nwv;
    if (nwv != 0.f) {
        atomicAdd(&AX[d * FH + f], -nwv * ldf(x, s * FH + f, f32));
        atomicAdd(&AH[d * FH + f], -nwv * ldf(H, s * FH + f, f32));
    }
}

// ---------------------------------------------------------------------------
// Kernel 4: per node: Z = sigmoid(cheb_xz(x) + cheb_hz(H)),
//                     R = sigmoid(cheb_xr(x) + cheb_hr(H)),  HR = H*R
// AGG arrays already carry tx1's minus sign. 8 nodes/block.
// ---------------------------------------------------------------------------
__global__ __launch_bounds__(256) void k_node_zr(
    const void* __restrict__ x, const void* __restrict__ H,
    const int* __restrict__ flg,
    const float* __restrict__ AX, const float* __restrict__ AH,
    const void* __restrict__ Wxz, const void* __restrict__ bxz,
    const void* __restrict__ Whz, const void* __restrict__ bhz,
    const void* __restrict__ Wxr, const void* __restrict__ bxr,
    const void* __restrict__ Whr, const void* __restrict__ bhr,
    float* __restrict__ Z, float* __restrict__ HR) {
    __shared__ float sWxz[2048], sWhz[2048], sWxr[2048], sWhr[2048];
    __shared__ float sbz[FH], sbr[FH];
    __shared__ float sv[8][4][FH];  // x, H, AX, AH

    int t = threadIdx.x;
    int f32 = flg[0];
    for (int i = t; i < 2048; i += 256) {
        sWxz[i] = ldf(Wxz, i, f32);
        sWhz[i] = ldf(Whz, i, f32);
        sWxr[i] = ldf(Wxr, i, f32);
        sWhr[i] = ldf(Whr, i, f32);
    }
    if (t < FH) {
        sbz[t] = ldf(bxz, t, f32) + ldf(bhz, t, f32);
        sbr[t] = ldf(bxr, t, f32) + ldf(bhr, t, f32);
    }
    int ln = t >> 5, f = t & 31;
    int node = blockIdx.x * 8 + ln;
    if (node < NN) {
        sv[ln][0][f] = ldf(x, node * FH + f, f32);
        sv[ln][1][f] = ldf(H, node * FH + f, f32);
        sv[ln][2][f] = AX[node * FH + f];
        sv[ln][3][f] = AH[node * FH + f];
    }
    __syncthreads();
    if (node >= NN) return;

    float zacc = sbz[f], racc = sbr[f];
    #pragma unroll
    for (int k = 0; k < FH; k++) {
        float xv = sv[ln][0][k], hv = sv[ln][1][k];
        float axv = sv[ln][2][k], ahv = sv[ln][3][k];
        zacc += xv * sWxz[k * FH + f] + axv * sWxz[1024 + k * FH + f]
              + hv * sWhz[k * FH + f] + ahv * sWhz[1024 + k * FH + f];
        racc += xv * sWxr[k * FH + f] + axv * sWxr[1024 + k * FH + f]
              + hv * sWhr[k * FH + f] + ahv * sWhr[1024 + k * FH + f];
    }
    float zv = 1.f / (1.f + expf(-zacc));
    float rv = 1.f / (1.f + expf(-racc));
    Z[node * FH + f] = zv;
    HR[node * FH + f] = sv[ln][1][f] * rv;
}

// ---------------------------------------------------------------------------
// Kernel 5: AHR[d] += -nw * HR[s]
// ---------------------------------------------------------------------------
__global__ __launch_bounds__(256) void k_edge_agg2(const void* __restrict__ ei,
                                                   const int* __restrict__ flg,
                                                   const float* __restrict__ nw,
                                                   const float* __restrict__ HR,
                                                   float* __restrict__ AHR) {
    unsigned t = blockIdx.x * 256u + threadIdx.x;
    if (t >= (unsigned)EE * FH) return;
    int e = (int)(t >> 5);
    int f = (int)(t & 31);
    float nwv = nw[e];
    if (nwv != 0.f) {
        int i64 = flg[1];
        int s = ldi(ei, e, i64);
        int d = ldi(ei, EE + e, i64);
        atomicAdd(&AHR[d * FH + f], -nwv * HR[s * FH + f]);
    }
}

// ---------------------------------------------------------------------------
// Kernel 6: H~ = tanh(cheb_xh(x) + cheb_hh(HR)); h = Z*H + (1-Z)*H~
//           out = relu(h) @ lin_w + lin_b.
// d_out: [out N*4][h N*32], dtype = detected float dtype.
// ---------------------------------------------------------------------------
__global__ __launch_bounds__(256) void k_node_final(
    const void* __restrict__ x, const void* __restrict__ H,
    const int* __restrict__ flg,
    const float* __restrict__ AX, const float* __restrict__ Z,
    const float* __restrict__ HR, const float* __restrict__ AHR,
    const void* __restrict__ Wxh, const void* __restrict__ bxh,
    const void* __restrict__ Whh, const void* __restrict__ bhh,
    const void* __restrict__ lin_w, const void* __restrict__ lin_b,
    void* __restrict__ out) {
    __shared__ float sWxh[2048], sWhh[2048];
    __shared__ float sb[FH];
    __shared__ float slw[FH * FOUT];
    __shared__ float slb[FOUT];
    __shared__ float sv[8][4][FH];   // x, HR, AX, AHR
    __shared__ float sH[8][FH], sZ[8][FH];
    __shared__ float srh[8][FH];     // relu(h)

    int t = threadIdx.x;
    int f32 = flg[0];
    for (int i = t; i < 2048; i += 256) {
        sWxh[i] = ldf(Wxh, i, f32);
        sWhh[i] = ldf(Whh, i, f32);
    }
    if (t < FH) sb[t] = ldf(bxh, t, f32) + ldf(bhh, t, f32);
    if (t < FH * FOUT) slw[t] = ldf(lin_w, t, f32);
    if (t < FOUT) slb[t] = ldf(lin_b, t, f32);

    int ln = t >> 5, f = t & 31;
    int node = blockIdx.x * 8 + ln;
    if (node < NN) {
        sv[ln][0][f] = ldf(x, node * FH + f, f32);
        sv[ln][1][f] = HR[node * FH + f];
        sv[ln][2][f] = AX[node * FH + f];
        sv[ln][3][f] = AHR[node * FH + f];
        sH[ln][f] = ldf(H, node * FH + f, f32);
        sZ[ln][f] = Z[node * FH + f];
    }
    __syncthreads();

    if (node < NN) {
        float acc = sb[f];
        #pragma unroll
        for (int k = 0; k < FH; k++) {
            acc += sv[ln][0][k] * sWxh[k * FH + f]
                 + sv[ln][2][k] * sWxh[1024 + k * FH + f]
                 + sv[ln][1][k] * sWhh[k * FH + f]
                 + sv[ln][3][k] * sWhh[1024 + k * FH + f];
        }
        float ht = tanhf(acc);
        float zv = sZ[ln][f];
        float hval = zv * sH[ln][f] + (1.f - zv) * ht;
        stf(out, NN * FOUT + node * FH + f, f32, hval);
        srh[ln][f] = hval > 0.f ? hval : 0.f;
    }
    __syncthreads();

    if (t < 8 * FOUT) {
        int n2 = t >> 2, fo = t & 3;
        int node2 = blockIdx.x * 8 + n2;
        if (node2 < NN) {
            float acc = slb[fo];
            #pragma unroll
            for (int k = 0; k < FH; k++) acc += srh[n2][k] * slw[k * FOUT + fo];
            stf(out, node2 * FOUT + fo, f32, acc);
        }
    }
}

// ---------------------------------------------------------------------------
extern "C" void kernel_launch(void* const* d_in, const int* in_sizes, int n_in,
                              void* d_out, int out_size, void* d_ws, size_t ws_size,
                              hipStream_t stream) {
    const void* x   = d_in[0];
    const void* ei  = d_in[1];
    const void* ew  = d_in[2];
    const void* H   = d_in[3];
    const void* Wxz = d_in[4];
    const void* bxz = d_in[5];
    const void* Whz = d_in[6];
    const void* bhz = d_in[7];
    const void* Wxr = d_in[8];
    const void* bxr = d_in[9];
    const void* Whr = d_in[10];
    const void* bhr = d_in[11];
    const void* Wxh = d_in[12];
    const void* bxh = d_in[13];
    const void* Whh = d_in[14];
    const void* bhh = d_in[15];
    const void* lnw = d_in[16];
    const void* lnb = d_in[17];

    // Workspace layout: [flags 64B][deg N][AX N*32][AH N*32][AHR N*32]
    //                   [nw E][Z N*32][HR N*32]   (~71 MB of fp32)
    int*   flg = (int*)d_ws;
    float* deg = (float*)((char*)d_ws + 64);
    float* AX  = deg + NN;
    float* AH  = AX + (size_t)NN * FH;
    float* AHR = AH + (size_t)NN * FH;
    float* nw  = AHR + (size_t)NN * FH;
    float* Z   = nw + EE;
    float* HR  = Z + (size_t)NN * FH;

    // Zero the atomic accumulators (deg, AX, AH, AHR are contiguous).
    hipMemsetAsync(deg, 0, (size_t)(NN + 3 * NN * FH) * sizeof(float), stream);

    const int eb  = (EE + 255) / 256;          // edge-parallel blocks
    const int efb = (EE * FH + 255) / 256;     // (edge,feature)-parallel blocks
    const int nb  = (NN + 255) / 256;          // node-parallel blocks
    const int n8b = (NN + 7) / 8;              // 8 nodes / block

    k_detect<<<1, 256, 0, stream>>>(x, ei, flg);
    k_deg<<<eb, 256, 0, stream>>>(ei, ew, flg, deg);
    k_dinv<<<nb, 256, 0, stream>>>(deg);
    k_edge_agg1<<<efb, 256, 0, stream>>>(ei, ew, flg, deg, x, H, nw, AX, AH);
    k_node_zr<<<n8b, 256, 0, stream>>>(x, H, flg, AX, AH, Wxz, bxz, Whz, bhz,
                                       Wxr, bxr, Whr, bhr, Z, HR);
    k_edge_agg2<<<efb, 256, 0, stream>>>(ei, flg, nw, HR, AHR);
    k_node_final<<<n8b, 256, 0, stream>>>(x, H, flg, AX, Z, HR, AHR,
                                          Wxh, bxh, Whh, bhh, lnw, lnb, d_out);
}

// Round 4
// 826.704 us; speedup vs baseline: 1.0978x; 1.0978x over previous
//
#include <hip/hip_runtime.h>
#include <hip/hip_bf16.h>

typedef __hip_bfloat16 bf16;

#define NN   100000
#define EE   1600000
#define FH   32
#define FOUT 4

__device__ __forceinline__ float b2f(bf16 v) { return __bfloat162float(v); }

// Dtype-robust loads: flg[0]=1 -> float arrays are fp32 else bf16;
// flg[1]=1 -> edge_index is int64 else int32. Wave-uniform branches.
__device__ __forceinline__ float ldf(const void* p, int i, int f32) {
    return f32 ? ((const float*)p)[i] : b2f(((const bf16*)p)[i]);
}
__device__ __forceinline__ int ldi(const void* p, int i, int i64f) {
    return i64f ? (int)(((const long long*)p)[i]) : ((const int*)p)[i];
}
__device__ __forceinline__ void stf(void* p, int i, int f32, float v) {
    if (f32) ((float*)p)[i] = v;
    else     ((bf16*)p)[i] = __float2bfloat16(v);
}

// ---------------------------------------------------------------------------
// Kernel 0: dtype detection (1 block). fp32-as-bf16 reinterp gives huge/NaN
// values in even slots; int64 ids have all-zero odd 32-bit words.
// ---------------------------------------------------------------------------
__global__ __launch_bounds__(256) void k_detect(const void* __restrict__ x,
                                                const void* __restrict__ ei,
                                                int* __restrict__ flg) {
    __shared__ int s_f32[256], s_oddnz[256];
    int t = threadIdx.x;
    float v = b2f(((const bf16*)x)[t]);
    s_f32[t] = (!isfinite(v)) || (fabsf(v) > 100.f);
    int w32 = ((const int*)ei)[t];
    s_oddnz[t] = ((t & 1) && (w32 != 0)) ? 1 : 0;
    __syncthreads();
    if (t == 0) {
        int f32 = 0, oddnz = 0;
        for (int i = 0; i < 256; i++) { f32 |= s_f32[i]; oddnz |= s_oddnz[i]; }
        flg[0] = f32;           // 1 => fp32 float arrays (and fp32 output)
        flg[1] = oddnz ? 0 : 1; // 1 => int64 edge_index
    }
}

// ---------------------------------------------------------------------------
// Kernel 1: deg[s] += w (self-loops zeroed)  AND  cnt[d] += 1 (CSR histogram)
// ---------------------------------------------------------------------------
__global__ __launch_bounds__(256) void k_hist(const void* __restrict__ ei,
                                              const void* __restrict__ ew,
                                              const int* __restrict__ flg,
                                              float* __restrict__ deg,
                                              int* __restrict__ cnt) {
    int e = blockIdx.x * 256 + threadIdx.x;
    if (e >= EE) return;
    int f32 = flg[0], i64 = flg[1];
    int s = ldi(ei, e, i64);
    int d = ldi(ei, EE + e, i64);
    atomicAdd(&cnt[d], 1);
    float w = (s == d) ? 0.f : ldf(ew, e, f32);
    if (w != 0.f) atomicAdd(&deg[s], w);
}

// ---------------------------------------------------------------------------
// Kernel 2: deg -> dinv (in place)
// ---------------------------------------------------------------------------
__global__ __launch_bounds__(256) void k_dinv(float* __restrict__ deg) {
    int i = blockIdx.x * 256 + threadIdx.x;
    if (i >= NN) return;
    float dv = deg[i];
    deg[i] = (dv > 0.f) ? rsqrtf(dv) : 0.f;
}

// ---------------------------------------------------------------------------
// Kernel 3: exclusive scan of cnt -> off[0..NN], off[NN]=EE. Single block.
// 1024 threads, each scans a contiguous chunk; block-scan of partials in LDS.
// ---------------------------------------------------------------------------
__global__ __launch_bounds__(1024) void k_scan(const int* __restrict__ cnt,
                                               int* __restrict__ off) {
    const int T = 1024;
    const int per = (NN + T - 1) / T;  // 98
    __shared__ int partial[T];
    int t = threadIdx.x;
    int base = t * per;
    int sum = 0;
    for (int i = 0; i < per; i++) {
        int idx = base + i;
        if (idx < NN) sum += cnt[idx];
    }
    partial[t] = sum;
    __syncthreads();
    for (int ofs = 1; ofs < T; ofs <<= 1) {
        int v = (t >= ofs) ? partial[t - ofs] : 0;
        __syncthreads();
        partial[t] += v;
        __syncthreads();
    }
    int run = (t > 0) ? partial[t - 1] : 0;
    for (int i = 0; i < per; i++) {
        int idx = base + i;
        if (idx < NN) { off[idx] = run; run += cnt[idx]; }
    }
    if (t == T - 1) off[NN] = partial[T - 1];
}

// ---------------------------------------------------------------------------
// Kernel 4: fill CSR. slot = off[d] + (atomicSub(cnt[d]) - 1); cnt ends at 0.
// elist[slot] = (src, nw) packed 8B. nw = dinv[s]*w*dinv[d], self-loops -> 0.
// ---------------------------------------------------------------------------
__global__ __launch_bounds__(256) void k_fill(const void* __restrict__ ei,
                                              const void* __restrict__ ew,
                                              const int* __restrict__ flg,
                                              const float* __restrict__ dinv,
                                              const int* __restrict__ off,
                                              int* __restrict__ cnt,
                                              int2* __restrict__ elist) {
    int e = blockIdx.x * 256 + threadIdx.x;
    if (e >= EE) return;
    int f32 = flg[0], i64 = flg[1];
    int s = ldi(ei, e, i64);
    int d = ldi(ei, EE + e, i64);
    float w = (s == d) ? 0.f : ldf(ew, e, f32);
    float nwv = dinv[s] * w * dinv[d];
    int k = atomicSub(&cnt[d], 1);
    elist[off[d] + k - 1] = make_int2(s, __float_as_int(nwv));
}

// ---------------------------------------------------------------------------
// Kernel 5: gather-aggregate x and H.  AX[n][f] = -sum_j nw_j * x[src_j][f]
// 8 nodes/block, 32 lanes (features) per node. No atomics.
// ---------------------------------------------------------------------------
__global__ __launch_bounds__(256) void k_gather1(const int* __restrict__ off,
                                                 const int2* __restrict__ elist,
                                                 const int* __restrict__ flg,
                                                 const void* __restrict__ x,
                                                 const void* __restrict__ H,
                                                 float* __restrict__ AX,
                                                 float* __restrict__ AH) {
    int t = threadIdx.x;
    int node = blockIdx.x * 8 + (t >> 5);
    if (node >= NN) return;
    int f = t & 31;
    int f32 = flg[0];
    int beg = off[node], end = off[node + 1];
    float ax = 0.f, ah = 0.f;
    int2 e = (beg < end) ? elist[beg] : make_int2(0, 0);
    for (int j = beg; j < end; j++) {
        int2 cur = e;
        if (j + 1 < end) e = elist[j + 1];
        float nwv = __int_as_float(cur.y);
        ax += nwv * ldf(x, cur.x * FH + f, f32);
        ah += nwv * ldf(H, cur.x * FH + f, f32);
    }
    AX[node * FH + f] = -ax;
    AH[node * FH + f] = -ah;
}

// ---------------------------------------------------------------------------
// Kernel 6: per node: Z = sigmoid(cheb_xz(x)+cheb_hz(H)),
//                     R = sigmoid(cheb_xr(x)+cheb_hr(H)), HR = H*R.
// ---------------------------------------------------------------------------
__global__ __launch_bounds__(256) void k_node_zr(
    const void* __restrict__ x, const void* __restrict__ H,
    const int* __restrict__ flg,
    const float* __restrict__ AX, const float* __restrict__ AH,
    const void* __restrict__ Wxz, const void* __restrict__ bxz,
    const void* __restrict__ Whz, const void* __restrict__ bhz,
    const void* __restrict__ Wxr, const void* __restrict__ bxr,
    const void* __restrict__ Whr, const void* __restrict__ bhr,
    float* __restrict__ Z, float* __restrict__ HR) {
    __shared__ float sWxz[2048], sWhz[2048], sWxr[2048], sWhr[2048];
    __shared__ float sbz[FH], sbr[FH];
    __shared__ float sv[8][4][FH];  // x, H, AX, AH

    int t = threadIdx.x;
    int f32 = flg[0];
    for (int i = t; i < 2048; i += 256) {
        sWxz[i] = ldf(Wxz, i, f32);
        sWhz[i] = ldf(Whz, i, f32);
        sWxr[i] = ldf(Wxr, i, f32);
        sWhr[i] = ldf(Whr, i, f32);
    }
    if (t < FH) {
        sbz[t] = ldf(bxz, t, f32) + ldf(bhz, t, f32);
        sbr[t] = ldf(bxr, t, f32) + ldf(bhr, t, f32);
    }
    int ln = t >> 5, f = t & 31;
    int node = blockIdx.x * 8 + ln;
    if (node < NN) {
        sv[ln][0][f] = ldf(x, node * FH + f, f32);
        sv[ln][1][f] = ldf(H, node * FH + f, f32);
        sv[ln][2][f] = AX[node * FH + f];
        sv[ln][3][f] = AH[node * FH + f];
    }
    __syncthreads();
    if (node >= NN) return;

    float zacc = sbz[f], racc = sbr[f];
    #pragma unroll
    for (int k = 0; k < FH; k++) {
        float xv = sv[ln][0][k], hv = sv[ln][1][k];
        float axv = sv[ln][2][k], ahv = sv[ln][3][k];
        zacc += xv * sWxz[k * FH + f] + axv * sWxz[1024 + k * FH + f]
              + hv * sWhz[k * FH + f] + ahv * sWhz[1024 + k * FH + f];
        racc += xv * sWxr[k * FH + f] + axv * sWxr[1024 + k * FH + f]
              + hv * sWhr[k * FH + f] + ahv * sWhr[1024 + k * FH + f];
    }
    float zv = 1.f / (1.f + expf(-zacc));
    float rv = 1.f / (1.f + expf(-racc));
    Z[node * FH + f] = zv;
    HR[node * FH + f] = sv[ln][1][f] * rv;
}

// ---------------------------------------------------------------------------
// Kernel 7: gather-aggregate HR.  AHR[n][f] = -sum_j nw_j * HR[src_j][f]
// ---------------------------------------------------------------------------
__global__ __launch_bounds__(256) void k_gather2(const int* __restrict__ off,
                                                 const int2* __restrict__ elist,
                                                 const float* __restrict__ HR,
                                                 float* __restrict__ AHR) {
    int t = threadIdx.x;
    int node = blockIdx.x * 8 + (t >> 5);
    if (node >= NN) return;
    int f = t & 31;
    int beg = off[node], end = off[node + 1];
    float acc = 0.f;
    int2 e = (beg < end) ? elist[beg] : make_int2(0, 0);
    for (int j = beg; j < end; j++) {
        int2 cur = e;
        if (j + 1 < end) e = elist[j + 1];
        acc += __int_as_float(cur.y) * HR[cur.x * FH + f];
    }
    AHR[node * FH + f] = -acc;
}

// ---------------------------------------------------------------------------
// Kernel 8: H~ = tanh(cheb_xh(x)+cheb_hh(HR)); h = Z*H + (1-Z)*H~;
//           out = relu(h) @ lin_w + lin_b.  d_out: [out N*4][h N*32].
// ---------------------------------------------------------------------------
__global__ __launch_bounds__(256) void k_node_final(
    const void* __restrict__ x, const void* __restrict__ H,
    const int* __restrict__ flg,
    const float* __restrict__ AX, const float* __restrict__ Z,
    const float* __restrict__ HR, const float* __restrict__ AHR,
    const void* __restrict__ Wxh, const void* __restrict__ bxh,
    const void* __restrict__ Whh, const void* __restrict__ bhh,
    const void* __restrict__ lin_w, const void* __restrict__ lin_b,
    void* __restrict__ out) {
    __shared__ float sWxh[2048], sWhh[2048];
    __shared__ float sb[FH];
    __shared__ float slw[FH * FOUT];
    __shared__ float slb[FOUT];
    __shared__ float sv[8][4][FH];   // x, HR, AX, AHR
    __shared__ float sH[8][FH], sZ[8][FH];
    __shared__ float srh[8][FH];     // relu(h)

    int t = threadIdx.x;
    int f32 = flg[0];
    for (int i = t; i < 2048; i += 256) {
        sWxh[i] = ldf(Wxh, i, f32);
        sWhh[i] = ldf(Whh, i, f32);
    }
    if (t < FH) sb[t] = ldf(bxh, t, f32) + ldf(bhh, t, f32);
    if (t < FH * FOUT) slw[t] = ldf(lin_w, t, f32);
    if (t < FOUT) slb[t] = ldf(lin_b, t, f32);

    int ln = t >> 5, f = t & 31;
    int node = blockIdx.x * 8 + ln;
    if (node < NN) {
        sv[ln][0][f] = ldf(x, node * FH + f, f32);
        sv[ln][1][f] = HR[node * FH + f];
        sv[ln][2][f] = AX[node * FH + f];
        sv[ln][3][f] = AHR[node * FH + f];
        sH[ln][f] = ldf(H, node * FH + f, f32);
        sZ[ln][f] = Z[node * FH + f];
    }
    __syncthreads();

    if (node < NN) {
        float acc = sb[f];
        #pragma unroll
        for (int k = 0; k < FH; k++) {
            acc += sv[ln][0][k] * sWxh[k * FH + f]
                 + sv[ln][2][k] * sWxh[1024 + k * FH + f]
                 + sv[ln][1][k] * sWhh[k * FH + f]
                 + sv[ln][3][k] * sWhh[1024 + k * FH + f];
        }
        float ht = tanhf(acc);
        float zv = sZ[ln][f];
        float hval = zv * sH[ln][f] + (1.f - zv) * ht;
        stf(out, NN * FOUT + node * FH + f, f32, hval);
        srh[ln][f] = hval > 0.f ? hval : 0.f;
    }
    __syncthreads();

    if (t < 8 * FOUT) {
        int n2 = t >> 2, fo = t & 3;
        int node2 = blockIdx.x * 8 + n2;
        if (node2 < NN) {
            float acc = slb[fo];
            #pragma unroll
            for (int k = 0; k < FH; k++) acc += srh[n2][k] * slw[k * FOUT + fo];
            stf(out, node2 * FOUT + fo, f32, acc);
        }
    }
}

// ---------------------------------------------------------------------------
extern "C" void kernel_launch(void* const* d_in, const int* in_sizes, int n_in,
                              void* d_out, int out_size, void* d_ws, size_t ws_size,
                              hipStream_t stream) {
    const void* x   = d_in[0];
    const void* ei  = d_in[1];
    const void* ew  = d_in[2];
    const void* H   = d_in[3];
    const void* Wxz = d_in[4];
    const void* bxz = d_in[5];
    const void* Whz = d_in[6];
    const void* bhz = d_in[7];
    const void* Wxr = d_in[8];
    const void* bxr = d_in[9];
    const void* Whr = d_in[10];
    const void* bhr = d_in[11];
    const void* Wxh = d_in[12];
    const void* bxh = d_in[13];
    const void* Whh = d_in[14];
    const void* bhh = d_in[15];
    const void* lnw = d_in[16];
    const void* lnb = d_in[17];

    // Workspace layout (bytes, 64-aligned sections):
    // [flg 64][deg N*4][cnt N*4][off (N+1)*4 pad][elist E*8]
    // [AX N*32*4][AHb N*32*4 (AH then AHR)][Z N*32*4][HR N*32*4]  ~65 MB
    char* base = (char*)d_ws;
    int*   flg   = (int*)base;                      base += 64;
    float* deg   = (float*)base;                    base += (size_t)NN * 4;
    int*   cnt   = (int*)base;                      base += (size_t)NN * 4;
    int*   off   = (int*)base;                      base += ((size_t)(NN + 1) * 4 + 63) & ~63ull;
    int2*  elist = (int2*)base;                     base += (size_t)EE * 8;
    float* AX    = (float*)base;                    base += (size_t)NN * FH * 4;
    float* AHb   = (float*)base;                    base += (size_t)NN * FH * 4; // AH, then AHR
    float* Z     = (float*)base;                    base += (size_t)NN * FH * 4;
    float* HR    = (float*)base;

    // Zero deg + cnt (contiguous, 800 KB).
    hipMemsetAsync(deg, 0, (size_t)NN * 8, stream);

    const int eb  = (EE + 255) / 256;   // edge-parallel blocks
    const int nb  = (NN + 255) / 256;   // node-parallel blocks
    const int n8b = (NN + 7) / 8;       // 8 nodes / block

    k_detect<<<1, 256, 0, stream>>>(x, ei, flg);
    k_hist<<<eb, 256, 0, stream>>>(ei, ew, flg, deg, cnt);
    k_dinv<<<nb, 256, 0, stream>>>(deg);
    k_scan<<<1, 1024, 0, stream>>>(cnt, off);
    k_fill<<<eb, 256, 0, stream>>>(ei, ew, flg, deg, off, cnt, elist);
    k_gather1<<<n8b, 256, 0, stream>>>(off, elist, flg, x, H, AX, AHb);
    k_node_zr<<<n8b, 256, 0, stream>>>(x, H, flg, AX, AHb, Wxz, bxz, Whz, bhz,
                                       Wxr, bxr, Whr, bhr, Z, HR);
    k_gather2<<<n8b, 256, 0, stream>>>(off, elist, HR, AHb);  // AHb now = AHR
    k_node_final<<<n8b, 256, 0, stream>>>(x, H, flg, AX, Z, HR, AHb,
                                          Wxh, bxh, Whh, bhh, lnw, lnb, d_out);
}

// Round 5
// 643.429 us; speedup vs baseline: 1.4105x; 1.2848x over previous
//
#include <hip/hip_runtime.h>
#include <hip/hip_bf16.h>

typedef __hip_bfloat16 bf16;

#define NN   100000
#define EE   1600000
#define FH   32
#define FOUT 4
#define SCAN_NB ((NN + 255) / 256)   // 391

__device__ __forceinline__ float b2f(bf16 v) { return __bfloat162float(v); }

// Dtype-robust loads: flg[0]=1 -> float arrays are fp32 else bf16;
// flg[1]=1 -> edge_index is int64 else int32. Wave-uniform branches.
__device__ __forceinline__ float ldf(const void* p, int i, int f32) {
    return f32 ? ((const float*)p)[i] : b2f(((const bf16*)p)[i]);
}
__device__ __forceinline__ int ldi(const void* p, int i, int i64f) {
    return i64f ? (int)(((const long long*)p)[i]) : ((const int*)p)[i];
}
__device__ __forceinline__ void stf(void* p, int i, int f32, float v) {
    if (f32) ((float*)p)[i] = v;
    else     ((bf16*)p)[i] = __float2bfloat16(v);
}

// ---------------------------------------------------------------------------
// Kernel 0: dtype detection (1 block). fp32-as-bf16 reinterp gives huge/NaN
// values in even slots; int64 ids have all-zero odd 32-bit words.
// ---------------------------------------------------------------------------
__global__ __launch_bounds__(256) void k_detect(const void* __restrict__ x,
                                                const void* __restrict__ ei,
                                                int* __restrict__ flg) {
    __shared__ int s_f32[256], s_oddnz[256];
    int t = threadIdx.x;
    float v = b2f(((const bf16*)x)[t]);
    s_f32[t] = (!isfinite(v)) || (fabsf(v) > 100.f);
    int w32 = ((const int*)ei)[t];
    s_oddnz[t] = ((t & 1) && (w32 != 0)) ? 1 : 0;
    __syncthreads();
    if (t == 0) {
        int f32 = 0, oddnz = 0;
        for (int i = 0; i < 256; i++) { f32 |= s_f32[i]; oddnz |= s_oddnz[i]; }
        flg[0] = f32;           // 1 => fp32 float arrays (and fp32 output)
        flg[1] = oddnz ? 0 : 1; // 1 => int64 edge_index
    }
}

// ---------------------------------------------------------------------------
// Kernel 1: deg[s] += w (self-loops zeroed)  AND  cnt[d] += 1 (CSR histogram)
// ---------------------------------------------------------------------------
__global__ __launch_bounds__(256) void k_hist(const void* __restrict__ ei,
                                              const void* __restrict__ ew,
                                              const int* __restrict__ flg,
                                              float* __restrict__ deg,
                                              int* __restrict__ cnt) {
    int e = blockIdx.x * 256 + threadIdx.x;
    if (e >= EE) return;
    int f32 = flg[0], i64 = flg[1];
    int s = ldi(ei, e, i64);
    int d = ldi(ei, EE + e, i64);
    atomicAdd(&cnt[d], 1);
    float w = (s == d) ? 0.f : ldf(ew, e, f32);
    if (w != 0.f) atomicAdd(&deg[s], w);
}

// ---------------------------------------------------------------------------
// Kernel 2: deg -> dinv (in place)
// ---------------------------------------------------------------------------
__global__ __launch_bounds__(256) void k_dinv(float* __restrict__ deg) {
    int i = blockIdx.x * 256 + threadIdx.x;
    if (i >= NN) return;
    float dv = deg[i];
    deg[i] = (dv > 0.f) ? rsqrtf(dv) : 0.f;
}

// ---------------------------------------------------------------------------
// Hierarchical exclusive scan of cnt -> off.  Phase A: per-block sums.
// ---------------------------------------------------------------------------
__global__ __launch_bounds__(256) void k_scan_a(const int* __restrict__ cnt,
                                                int* __restrict__ bsum) {
    __shared__ int s[256];
    int t = threadIdx.x;
    int i = blockIdx.x * 256 + t;
    s[t] = (i < NN) ? cnt[i] : 0;
    __syncthreads();
    for (int ofs = 128; ofs > 0; ofs >>= 1) {
        if (t < ofs) s[t] += s[t + ofs];
        __syncthreads();
    }
    if (t == 0) bsum[blockIdx.x] = s[0];
}

// Phase B: exclusive scan of the SCAN_NB block sums (1 block, 512 threads).
__global__ __launch_bounds__(512) void k_scan_b(int* __restrict__ bsum) {
    __shared__ int s[512];
    int t = threadIdx.x;
    int v = (t < SCAN_NB) ? bsum[t] : 0;
    s[t] = v;
    __syncthreads();
    for (int ofs = 1; ofs < 512; ofs <<= 1) {
        int u = (t >= ofs) ? s[t - ofs] : 0;
        __syncthreads();
        s[t] += u;
        __syncthreads();
    }
    if (t < SCAN_NB) bsum[t] = s[t] - v;   // exclusive
}

// Phase C: per-block exclusive scan + block offset -> off; off[NN] = EE.
__global__ __launch_bounds__(256) void k_scan_c(const int* __restrict__ cnt,
                                                const int* __restrict__ bsum,
                                                int* __restrict__ off) {
    __shared__ int s[256];
    int t = threadIdx.x;
    int i = blockIdx.x * 256 + t;
    int v = (i < NN) ? cnt[i] : 0;
    s[t] = v;
    __syncthreads();
    for (int ofs = 1; ofs < 256; ofs <<= 1) {
        int u = (t >= ofs) ? s[t - ofs] : 0;
        __syncthreads();
        s[t] += u;
        __syncthreads();
    }
    if (i < NN) off[i] = bsum[blockIdx.x] + s[t] - v;
    if (i == 0) off[NN] = EE;
}

// ---------------------------------------------------------------------------
// Kernel 4: fill CSR. slot = off[d] + (atomicSub(cnt[d]) - 1); cnt ends at 0.
// elist[slot] = (src, nw) packed 8B. nw = dinv[s]*w*dinv[d], self-loops -> 0.
// ---------------------------------------------------------------------------
__global__ __launch_bounds__(256) void k_fill(const void* __restrict__ ei,
                                              const void* __restrict__ ew,
                                              const int* __restrict__ flg,
                                              const float* __restrict__ dinv,
                                              const int* __restrict__ off,
                                              int* __restrict__ cnt,
                                              int2* __restrict__ elist) {
    int e = blockIdx.x * 256 + threadIdx.x;
    if (e >= EE) return;
    int f32 = flg[0], i64 = flg[1];
    int s = ldi(ei, e, i64);
    int d = ldi(ei, EE + e, i64);
    float w = (s == d) ? 0.f : ldf(ew, e, f32);
    float nwv = dinv[s] * w * dinv[d];
    int k = atomicSub(&cnt[d], 1);
    elist[off[d] + k - 1] = make_int2(s, __float_as_int(nwv));
}

// ---------------------------------------------------------------------------
// Kernel 5: gather-aggregate x and H.  AX[n][f] = -sum_j nw_j * x[src_j][f]
// 8 nodes/block, 32 lanes (features) per node. No atomics.
// ---------------------------------------------------------------------------
__global__ __launch_bounds__(256) void k_gather1(const int* __restrict__ off,
                                                 const int2* __restrict__ elist,
                                                 const int* __restrict__ flg,
                                                 const void* __restrict__ x,
                                                 const void* __restrict__ H,
                                                 float* __restrict__ AX,
                                                 float* __restrict__ AH) {
    int t = threadIdx.x;
    int node = blockIdx.x * 8 + (t >> 5);
    if (node >= NN) return;
    int f = t & 31;
    int f32 = flg[0];
    int beg = off[node], end = off[node + 1];
    float ax = 0.f, ah = 0.f;
    int2 e = (beg < end) ? elist[beg] : make_int2(0, 0);
    for (int j = beg; j < end; j++) {
        int2 cur = e;
        if (j + 1 < end) e = elist[j + 1];
        float nwv = __int_as_float(cur.y);
        ax += nwv * ldf(x, cur.x * FH + f, f32);
        ah += nwv * ldf(H, cur.x * FH + f, f32);
    }
    AX[node * FH + f] = -ax;
    AH[node * FH + f] = -ah;
}

// ---------------------------------------------------------------------------
// Kernel 6: per node: Z = sigmoid(cheb_xz(x)+cheb_hz(H)),
//                     R = sigmoid(cheb_xr(x)+cheb_hr(H)), HR = H*R.
// ---------------------------------------------------------------------------
__global__ __launch_bounds__(256) void k_node_zr(
    const void* __restrict__ x, const void* __restrict__ H,
    const int* __restrict__ flg,
    const float* __restrict__ AX, const float* __restrict__ AH,
    const void* __restrict__ Wxz, const void* __restrict__ bxz,
    const void* __restrict__ Whz, const void* __restrict__ bhz,
    const void* __restrict__ Wxr, const void* __restrict__ bxr,
    const void* __restrict__ Whr, const void* __restrict__ bhr,
    float* __restrict__ Z, float* __restrict__ HR) {
    __shared__ float sWxz[2048], sWhz[2048], sWxr[2048], sWhr[2048];
    __shared__ float sbz[FH], sbr[FH];
    __shared__ float sv[8][4][FH];  // x, H, AX, AH

    int t = threadIdx.x;
    int f32 = flg[0];
    for (int i = t; i < 2048; i += 256) {
        sWxz[i] = ldf(Wxz, i, f32);
        sWhz[i] = ldf(Whz, i, f32);
        sWxr[i] = ldf(Wxr, i, f32);
        sWhr[i] = ldf(Whr, i, f32);
    }
    if (t < FH) {
        sbz[t] = ldf(bxz, t, f32) + ldf(bhz, t, f32);
        sbr[t] = ldf(bxr, t, f32) + ldf(bhr, t, f32);
    }
    int ln = t >> 5, f = t & 31;
    int node = blockIdx.x * 8 + ln;
    if (node < NN) {
        sv[ln][0][f] = ldf(x, node * FH + f, f32);
        sv[ln][1][f] = ldf(H, node * FH + f, f32);
        sv[ln][2][f] = AX[node * FH + f];
        sv[ln][3][f] = AH[node * FH + f];
    }
    __syncthreads();
    if (node >= NN) return;

    float zacc = sbz[f], racc = sbr[f];
    #pragma unroll
    for (int k = 0; k < FH; k++) {
        float xv = sv[ln][0][k], hv = sv[ln][1][k];
        float axv = sv[ln][2][k], ahv = sv[ln][3][k];
        zacc += xv * sWxz[k * FH + f] + axv * sWxz[1024 + k * FH + f]
              + hv * sWhz[k * FH + f] + ahv * sWhz[1024 + k * FH + f];
        racc += xv * sWxr[k * FH + f] + axv * sWxr[1024 + k * FH + f]
              + hv * sWhr[k * FH + f] + ahv * sWhr[1024 + k * FH + f];
    }
    float zv = 1.f / (1.f + expf(-zacc));
    float rv = 1.f / (1.f + expf(-racc));
    Z[node * FH + f] = zv;
    HR[node * FH + f] = sv[ln][1][f] * rv;
}

// ---------------------------------------------------------------------------
// Kernel 7: gather-aggregate HR.  AHR[n][f] = -sum_j nw_j * HR[src_j][f]
// ---------------------------------------------------------------------------
__global__ __launch_bounds__(256) void k_gather2(const int* __restrict__ off,
                                                 const int2* __restrict__ elist,
                                                 const float* __restrict__ HR,
                                                 float* __restrict__ AHR) {
    int t = threadIdx.x;
    int node = blockIdx.x * 8 + (t >> 5);
    if (node >= NN) return;
    int f = t & 31;
    int beg = off[node], end = off[node + 1];
    float acc = 0.f;
    int2 e = (beg < end) ? elist[beg] : make_int2(0, 0);
    for (int j = beg; j < end; j++) {
        int2 cur = e;
        if (j + 1 < end) e = elist[j + 1];
        acc += __int_as_float(cur.y) * HR[cur.x * FH + f];
    }
    AHR[node * FH + f] = -acc;
}

// ---------------------------------------------------------------------------
// Kernel 8: H~ = tanh(cheb_xh(x)+cheb_hh(HR)); h = Z*H + (1-Z)*H~;
//           out = relu(h) @ lin_w + lin_b.  d_out: [out N*4][h N*32].
// ---------------------------------------------------------------------------
__global__ __launch_bounds__(256) void k_node_final(
    const void* __restrict__ x, const void* __restrict__ H,
    const int* __restrict__ flg,
    const float* __restrict__ AX, const float* __restrict__ Z,
    const float* __restrict__ HR, const float* __restrict__ AHR,
    const void* __restrict__ Wxh, const void* __restrict__ bxh,
    const void* __restrict__ Whh, const void* __restrict__ bhh,
    const void* __restrict__ lin_w, const void* __restrict__ lin_b,
    void* __restrict__ out) {
    __shared__ float sWxh[2048], sWhh[2048];
    __shared__ float sb[FH];
    __shared__ float slw[FH * FOUT];
    __shared__ float slb[FOUT];
    __shared__ float sv[8][4][FH];   // x, HR, AX, AHR
    __shared__ float sH[8][FH], sZ[8][FH];
    __shared__ float srh[8][FH];     // relu(h)

    int t = threadIdx.x;
    int f32 = flg[0];
    for (int i = t; i < 2048; i += 256) {
        sWxh[i] = ldf(Wxh, i, f32);
        sWhh[i] = ldf(Whh, i, f32);
    }
    if (t < FH) sb[t] = ldf(bxh, t, f32) + ldf(bhh, t, f32);
    if (t < FH * FOUT) slw[t] = ldf(lin_w, t, f32);
    if (t < FOUT) slb[t] = ldf(lin_b, t, f32);

    int ln = t >> 5, f = t & 31;
    int node = blockIdx.x * 8 + ln;
    if (node < NN) {
        sv[ln][0][f] = ldf(x, node * FH + f, f32);
        sv[ln][1][f] = HR[node * FH + f];
        sv[ln][2][f] = AX[node * FH + f];
        sv[ln][3][f] = AHR[node * FH + f];
        sH[ln][f] = ldf(H, node * FH + f, f32);
        sZ[ln][f] = Z[node * FH + f];
    }
    __syncthreads();

    if (node < NN) {
        float acc = sb[f];
        #pragma unroll
        for (int k = 0; k < FH; k++) {
            acc += sv[ln][0][k] * sWxh[k * FH + f]
                 + sv[ln][2][k] * sWxh[1024 + k * FH + f]
                 + sv[ln][1][k] * sWhh[k * FH + f]
                 + sv[ln][3][k] * sWhh[1024 + k * FH + f];
        }
        float ht = tanhf(acc);
        float zv = sZ[ln][f];
        float hval = zv * sH[ln][f] + (1.f - zv) * ht;
        stf(out, NN * FOUT + node * FH + f, f32, hval);
        srh[ln][f] = hval > 0.f ? hval : 0.f;
    }
    __syncthreads();

    if (t < 8 * FOUT) {
        int n2 = t >> 2, fo = t & 3;
        int node2 = blockIdx.x * 8 + n2;
        if (node2 < NN) {
            float acc = slb[fo];
            #pragma unroll
            for (int k = 0; k < FH; k++) acc += srh[n2][k] * slw[k * FOUT + fo];
            stf(out, node2 * FOUT + fo, f32, acc);
        }
    }
}

// ---------------------------------------------------------------------------
extern "C" void kernel_launch(void* const* d_in, const int* in_sizes, int n_in,
                              void* d_out, int out_size, void* d_ws, size_t ws_size,
                              hipStream_t stream) {
    const void* x   = d_in[0];
    const void* ei  = d_in[1];
    const void* ew  = d_in[2];
    const void* H   = d_in[3];
    const void* Wxz = d_in[4];
    const void* bxz = d_in[5];
    const void* Whz = d_in[6];
    const void* bhz = d_in[7];
    const void* Wxr = d_in[8];
    const void* bxr = d_in[9];
    const void* Whr = d_in[10];
    const void* bhr = d_in[11];
    const void* Wxh = d_in[12];
    const void* bxh = d_in[13];
    const void* Whh = d_in[14];
    const void* bhh = d_in[15];
    const void* lnw = d_in[16];
    const void* lnb = d_in[17];

    // Workspace layout (bytes, 64-aligned sections):
    // [flg 64][deg N*4][cnt N*4][off (N+1)*4 pad][bsum SCAN_NB*4 pad]
    // [elist E*8][AX N*32*4][AHb N*32*4][Z N*32*4][HR N*32*4]  ~65 MB
    char* base = (char*)d_ws;
    int*   flg   = (int*)base;   base += 64;
    float* deg   = (float*)base; base += (size_t)NN * 4;
    int*   cnt   = (int*)base;   base += (size_t)NN * 4;
    int*   off   = (int*)base;   base += ((size_t)(NN + 1) * 4 + 63) & ~63ull;
    int*   bsum  = (int*)base;   base += ((size_t)SCAN_NB * 4 + 63) & ~63ull;
    int2*  elist = (int2*)base;  base += (size_t)EE * 8;
    float* AX    = (float*)base; base += (size_t)NN * FH * 4;
    float* AHb   = (float*)base; base += (size_t)NN * FH * 4; // AH, then AHR
    float* Z     = (float*)base; base += (size_t)NN * FH * 4;
    float* HR    = (float*)base;

    // Zero deg + cnt (contiguous, 800 KB).
    hipMemsetAsync(deg, 0, (size_t)NN * 8, stream);

    const int eb  = (EE + 255) / 256;   // edge-parallel blocks
    const int nb  = (NN + 255) / 256;   // node-parallel blocks
    const int n8b = (NN + 7) / 8;       // 8 nodes / block

    k_detect<<<1, 256, 0, stream>>>(x, ei, flg);
    k_hist<<<eb, 256, 0, stream>>>(ei, ew, flg, deg, cnt);
    k_dinv<<<nb, 256, 0, stream>>>(deg);
    k_scan_a<<<SCAN_NB, 256, 0, stream>>>(cnt, bsum);
    k_scan_b<<<1, 512, 0, stream>>>(bsum);
    k_scan_c<<<SCAN_NB, 256, 0, stream>>>(cnt, bsum, off);
    k_fill<<<eb, 256, 0, stream>>>(ei, ew, flg, deg, off, cnt, elist);
    k_gather1<<<n8b, 256, 0, stream>>>(off, elist, flg, x, H, AX, AHb);
    k_node_zr<<<n8b, 256, 0, stream>>>(x, H, flg, AX, AHb, Wxz, bxz, Whz, bhz,
                                       Wxr, bxr, Whr, bhr, Z, HR);
    k_gather2<<<n8b, 256, 0, stream>>>(off, elist, HR, AHb);  // AHb now = AHR
    k_node_final<<<n8b, 256, 0, stream>>>(x, H, flg, AX, Z, HR, AHb,
                                          Wxh, bxh, Whh, bhh, lnw, lnb, d_out);
}